// Round 6
// baseline (222392.578 us; speedup 1.0000x reference)
//
#include <hip/hip_runtime.h>
#include <hip/hip_bf16.h>
#include <hip/hip_cooperative_groups.h>

namespace cg = cooperative_groups;

typedef unsigned short u16;
typedef unsigned int   u32;

#define S_  256
#define B_  512
#define H_  512
#define I_  70

#define SM_FLOATS 6240   // 24.96 KB: fits gru (24x260), b1 (4352), b2 (6144)

// ---- bf16 helpers ----
__device__ __forceinline__ float bfu(u16 u) {
    return __uint_as_float(((u32)u) << 16);
}
__device__ __forceinline__ u16 f2bf_u(float f) {
    __hip_bfloat16 h = __float2bfloat16(f);
    u16 r;
    __builtin_memcpy(&r, &h, 2);
    return r;
}
__device__ __forceinline__ float sigmoidf_(float x) {
    x = fminf(fmaxf(x, -30.f), 30.f);
    return 1.f / (1.f + __expf(-x));
}
__device__ __forceinline__ float tanhf_(float x) {
    x = fminf(fmaxf(x, -15.f), 15.f);
    float e = __expf(2.f * x);
    return (e - 1.f) / (e + 1.f);
}

// ---- diagnostic sentinel ----
__global__ __launch_bounds__(256)
void k_sentinel(float* __restrict__ out, int n, float v) {
    int i = blockIdx.x * 256 + threadIdx.x;
    if (i < n) out[i] = v;
}

// ---- h0 = patient @ Wi2h.T + bi2h ; init both layers' h state ----
__global__ __launch_bounds__(256)
void k_h0(const float* __restrict__ X, const float* __restrict__ Wi2h,
          const float* __restrict__ bi2h, float* __restrict__ h1a,
          float* __restrict__ h2a) {
    int idx = blockIdx.x * 256 + threadIdx.x;
    int b = idx >> 9, h = idx & 511;
    const float* xp = X + b * I_ + 64;
    const float* wp = Wi2h + h * 6;
    float s = bi2h[h];
    #pragma unroll
    for (int j = 0; j < 6; j++) s += xp[j] * wp[j];
    h1a[idx] = s;
    h2a[idx] = s;
}

// ---- beff[e] = bcomb2[e] + sum_h Wcomb2[e][512+h] ----
__global__ __launch_bounds__(256)
void k_beff(const float* __restrict__ Wcomb2, const float* __restrict__ bcomb2,
            float* __restrict__ beff) {
    int e = blockIdx.x * 256 + threadIdx.x;
    if (e >= 512) return;
    float s = bcomb2[e];
    const float* wp = Wcomb2 + (size_t)e * 1024 + 512;
    for (int k = 0; k < 512; k++) s += wp[k];
    beff[e] = s;
}

// ---- comb1 = concat(X[:,:,:64], M[:,:,:64]) @ Wcomb1.T + bcomb1 -> bf16 ----
__global__ __launch_bounds__(256)
void k_comb1(const float* __restrict__ X, const float* __restrict__ M,
             const float* __restrict__ Wcomb1, const float* __restrict__ bcomb1,
             u16* __restrict__ comb1) {
    __shared__ float W_s[128 * 68];
    __shared__ float in_s[16 * 132];
    const int tid = threadIdx.x;
    for (int i = tid; i < 64 * 128; i += 256) {
        int e = i >> 7, k = i & 127;
        W_s[k * 68 + e] = Wcomb1[i];
    }
    const size_t row0 = (size_t)blockIdx.x * 16;
    for (int i = tid; i < 16 * 128; i += 256) {
        int r = i >> 7, k = i & 127;
        size_t rg = row0 + r;
        in_s[r * 132 + k] = (k < 64) ? X[rg * I_ + k] : M[rg * I_ + (k - 64)];
    }
    __syncthreads();
    const int ty = tid >> 4, tx = tid & 15;
    float a0 = 0, a1 = 0, a2 = 0, a3 = 0;
    for (int k = 0; k < 128; k++) {
        float a = in_s[ty * 132 + k];
        float w[4];
        *(float4*)w = *(const float4*)&W_s[k * 68 + tx * 4];
        a0 = fmaf(a, w[0], a0); a1 = fmaf(a, w[1], a1);
        a2 = fmaf(a, w[2], a2); a3 = fmaf(a, w[3], a3);
    }
    size_t rg = row0 + ty;
    int e0 = tx * 4;
    ushort4 st;
    st.x = f2bf_u(a0 + bcomb1[e0 + 0]);
    st.y = f2bf_u(a1 + bcomb1[e0 + 1]);
    st.z = f2bf_u(a2 + bcomb1[e0 + 2]);
    st.w = f2bf_u(a3 + bcomb1[e0 + 3]);
    *(ushort4*)&comb1[rg * 64 + e0] = st;
}

// ================= device phases (shared by coop + fallback) =================

// GRU step. 512 blocks: blockIdx.x low6 = h-tile(8), high3 = b-tile(64).
// Weights staged in k-chunks of <=256 (LDS 24x260 f32 = 24.96 KB).
template<int D>
__device__ void gru_phase(float* __restrict__ W_s,
                          const u16* __restrict__ comb_t,
                          const float* __restrict__ Wih,
                          const float* __restrict__ Whh,
                          const float* __restrict__ bih,
                          const float* __restrict__ bhh,
                          const float* __restrict__ maskRow,
                          const float* __restrict__ hcur,
                          float* __restrict__ hnxt) {
    const int tid = threadIdx.x;
    const int hl = tid & 7;
    const int ty = tid >> 3;
    const int h0 = (blockIdx.x & 63) * 8;
    const int h  = h0 + hl;
    const int b  = (blockIdx.x >> 6) * 64 + ty * 2;

    const float* hr0 = hcur + (size_t)b * 512;
    const float* hr1 = hcur + (size_t)(b + 1) * 512;
    float gh00 = bhh[h], gh10 = bhh[512 + h], gh20 = bhh[1024 + h];
    float gh01 = gh00, gh11 = gh10, gh21 = gh20;

    // ---- gh = hx @ Whh.T, two k-chunks of 256 ----
    #pragma unroll
    for (int half = 0; half < 2; half++) {
        const int kbase = half * 256;
        __syncthreads();   // protect W_s from previous use
        for (int i = tid; i < 24 * 64; i += 256) {
            int r = i >> 6, kq = i & 63;
            int g = r >> 3, hh = r & 7;
            *(float4*)&W_s[r * 260 + kq * 4] =
                *(const float4*)&Whh[((size_t)(g * 512 + h0 + hh)) * 512 + kbase + kq * 4];
        }
        __syncthreads();
        const float* w0p = &W_s[(0 * 8 + hl) * 260];
        const float* w1p = &W_s[(1 * 8 + hl) * 260];
        const float* w2p = &W_s[(2 * 8 + hl) * 260];
        const float* hap = hr0 + kbase;
        const float* hbp = hr1 + kbase;
        for (int k = 0; k < 256; k += 4) {
            float4 w0 = *(const float4*)(w0p + k);
            float4 w1 = *(const float4*)(w1p + k);
            float4 w2 = *(const float4*)(w2p + k);
            float4 ha = *(const float4*)(hap + k);
            float4 hb = *(const float4*)(hbp + k);
            gh00 = fmaf(w0.x, ha.x, gh00); gh00 = fmaf(w0.y, ha.y, gh00);
            gh00 = fmaf(w0.z, ha.z, gh00); gh00 = fmaf(w0.w, ha.w, gh00);
            gh10 = fmaf(w1.x, ha.x, gh10); gh10 = fmaf(w1.y, ha.y, gh10);
            gh10 = fmaf(w1.z, ha.z, gh10); gh10 = fmaf(w1.w, ha.w, gh10);
            gh20 = fmaf(w2.x, ha.x, gh20); gh20 = fmaf(w2.y, ha.y, gh20);
            gh20 = fmaf(w2.z, ha.z, gh20); gh20 = fmaf(w2.w, ha.w, gh20);
            gh01 = fmaf(w0.x, hb.x, gh01); gh01 = fmaf(w0.y, hb.y, gh01);
            gh01 = fmaf(w0.z, hb.z, gh01); gh01 = fmaf(w0.w, hb.w, gh01);
            gh11 = fmaf(w1.x, hb.x, gh11); gh11 = fmaf(w1.y, hb.y, gh11);
            gh11 = fmaf(w1.z, hb.z, gh11); gh11 = fmaf(w1.w, hb.w, gh11);
            gh21 = fmaf(w2.x, hb.x, gh21); gh21 = fmaf(w2.y, hb.y, gh21);
            gh21 = fmaf(w2.z, hb.z, gh21); gh21 = fmaf(w2.w, hb.w, gh21);
        }
    }

    // ---- gi = comb_t @ Wih.T, k-chunks of CH ----
    constexpr int CH = (D < 256) ? D : 256;
    constexpr int ST = CH + 4;
    const u16* cr0 = comb_t + (size_t)b * D;
    const u16* cr1 = comb_t + (size_t)(b + 1) * D;
    float gi00 = bih[h], gi10 = bih[512 + h], gi20 = bih[1024 + h];
    float gi01 = gi00, gi11 = gi10, gi21 = gi20;
    #pragma unroll
    for (int kbase = 0; kbase < D; kbase += CH) {
        __syncthreads();
        for (int i = tid; i < 24 * (CH / 4); i += 256) {
            int r = i / (CH / 4), kq = i % (CH / 4);
            int g = r >> 3, hh = r & 7;
            *(float4*)&W_s[r * ST + kq * 4] =
                *(const float4*)&Wih[((size_t)(g * 512 + h0 + hh)) * D + kbase + kq * 4];
        }
        __syncthreads();
        const float* w0p = &W_s[(0 * 8 + hl) * ST];
        const float* w1p = &W_s[(1 * 8 + hl) * ST];
        const float* w2p = &W_s[(2 * 8 + hl) * ST];
        for (int k = 0; k < CH; k += 4) {
            float4 w0 = *(const float4*)(w0p + k);
            float4 w1 = *(const float4*)(w1p + k);
            float4 w2 = *(const float4*)(w2p + k);
            ushort4 cu0 = *(const ushort4*)(cr0 + kbase + k);
            ushort4 cu1 = *(const ushort4*)(cr1 + kbase + k);
            float ca[4] = {bfu(cu0.x), bfu(cu0.y), bfu(cu0.z), bfu(cu0.w)};
            float cb[4] = {bfu(cu1.x), bfu(cu1.y), bfu(cu1.z), bfu(cu1.w)};
            gi00 = fmaf(w0.x, ca[0], gi00); gi00 = fmaf(w0.y, ca[1], gi00);
            gi00 = fmaf(w0.z, ca[2], gi00); gi00 = fmaf(w0.w, ca[3], gi00);
            gi10 = fmaf(w1.x, ca[0], gi10); gi10 = fmaf(w1.y, ca[1], gi10);
            gi10 = fmaf(w1.z, ca[2], gi10); gi10 = fmaf(w1.w, ca[3], gi10);
            gi20 = fmaf(w2.x, ca[0], gi20); gi20 = fmaf(w2.y, ca[1], gi20);
            gi20 = fmaf(w2.z, ca[2], gi20); gi20 = fmaf(w2.w, ca[3], gi20);
            gi01 = fmaf(w0.x, cb[0], gi01); gi01 = fmaf(w0.y, cb[1], gi01);
            gi01 = fmaf(w0.z, cb[2], gi01); gi01 = fmaf(w0.w, cb[3], gi01);
            gi11 = fmaf(w1.x, cb[0], gi11); gi11 = fmaf(w1.y, cb[1], gi11);
            gi11 = fmaf(w1.z, cb[2], gi11); gi11 = fmaf(w1.w, cb[3], gi11);
            gi21 = fmaf(w2.x, cb[0], gi21); gi21 = fmaf(w2.y, cb[1], gi21);
            gi21 = fmaf(w2.z, cb[2], gi21); gi21 = fmaf(w2.w, cb[3], gi21);
        }
    }
    {
        float hold = hr0[h];
        float r = sigmoidf_(gi00 + gh00);
        float z = sigmoidf_(gi10 + gh10);
        float n = tanhf_(gi20 + r * gh20);
        float m = maskRow[b];
        hnxt[(size_t)b * 512 + h] = ((1.f - z) * n + z * hold) * m + hold * (1.f - m);
    }
    {
        float hold = hr1[h];
        float r = sigmoidf_(gi01 + gh01);
        float z = sigmoidf_(gi11 + gh11);
        float n = tanhf_(gi21 + r * gh21);
        float m = maskRow[b + 1];
        hnxt[(size_t)(b + 1) * 512 + h] = ((1.f - z) * n + z * hold) * m + hold * (1.f - m);
    }
}

// B1 phase: blocks 0..127, 4 rows each.
__device__ void b1_phase(float* __restrict__ sm,
                         const u16* __restrict__ c1t, const float* __restrict__ h1,
                         const float* __restrict__ Wc21, const float* __restrict__ bc21,
                         const float* __restrict__ lg1, const float* __restrict__ lb1,
                         const float* __restrict__ Wcomb2, const float* __restrict__ beff,
                         u16* __restrict__ c2t) {
    float* x_s = sm;            // 4*576
    float* y_s = sm + 4 * 576;  // 4*512
    const int tid = threadIdx.x;
    const int row0 = blockIdx.x * 4;
    for (int i = tid; i < 4 * 64; i += 256) {
        int r = i >> 6, k = i & 63;
        x_s[r * 576 + k] = bfu(c1t[(size_t)(row0 + r) * 64 + k]);
    }
    for (int i = tid; i < 4 * 512; i += 256) {
        int r = i >> 9, k = i & 511;
        x_s[r * 576 + 64 + k] = h1[(size_t)(row0 + r) * 512 + k];
    }
    __syncthreads();
    const int w = tid >> 6, lane = tid & 63;
    const int cg_ = lane >> 4, kl = lane & 15;
    for (int i = 0; i < 32; i++) {
        int o = i * 16 + w * 4 + cg_;
        const float* wrow = Wc21 + (size_t)o * 576;
        float racc[4] = {0.f, 0.f, 0.f, 0.f};
        #pragma unroll
        for (int g = 0; g < 9; g++) {
            int k = g * 64 + kl * 4;
            float4 wv = *(const float4*)(wrow + k);
            #pragma unroll
            for (int r = 0; r < 4; r++) {
                float4 xv = *(const float4*)(x_s + r * 576 + k);
                racc[r] = fmaf(wv.x, xv.x, racc[r]);
                racc[r] = fmaf(wv.y, xv.y, racc[r]);
                racc[r] = fmaf(wv.z, xv.z, racc[r]);
                racc[r] = fmaf(wv.w, xv.w, racc[r]);
            }
        }
        #pragma unroll
        for (int r = 0; r < 4; r++) {
            racc[r] += __shfl_xor(racc[r], 1, 64);
            racc[r] += __shfl_xor(racc[r], 2, 64);
            racc[r] += __shfl_xor(racc[r], 4, 64);
            racc[r] += __shfl_xor(racc[r], 8, 64);
        }
        if (kl == 0) {
            float bb = bc21[o];
            #pragma unroll
            for (int r = 0; r < 4; r++) y_s[r * 512 + o] = racc[r] + bb;
        }
    }
    __syncthreads();
    {
        float v[8], sum = 0.f, ssq = 0.f;
        #pragma unroll
        for (int j = 0; j < 8; j++) {
            v[j] = y_s[w * 512 + lane * 8 + j];
            sum += v[j]; ssq += v[j] * v[j];
        }
        #pragma unroll
        for (int m = 1; m < 64; m <<= 1) {
            sum += __shfl_xor(sum, m, 64);
            ssq += __shfl_xor(ssq, m, 64);
        }
        float mu = sum * (1.f / 512.f);
        float rstd = rsqrtf(ssq * (1.f / 512.f) - mu * mu + 1e-5f);
        #pragma unroll
        for (int j = 0; j < 8; j++) {
            int o = lane * 8 + j;
            y_s[w * 512 + o] = (v[j] - mu) * rstd * lg1[o] + lb1[o];
        }
    }
    __syncthreads();
    for (int i = 0; i < 32; i++) {
        int o = i * 16 + w * 4 + cg_;
        const float* wrow = Wcomb2 + (size_t)o * 1024;
        float racc[4] = {0.f, 0.f, 0.f, 0.f};
        #pragma unroll
        for (int g = 0; g < 8; g++) {
            int k = g * 64 + kl * 4;
            float4 wv = *(const float4*)(wrow + k);
            #pragma unroll
            for (int r = 0; r < 4; r++) {
                float4 xv = *(const float4*)(y_s + r * 512 + k);
                racc[r] = fmaf(wv.x, xv.x, racc[r]);
                racc[r] = fmaf(wv.y, xv.y, racc[r]);
                racc[r] = fmaf(wv.z, xv.z, racc[r]);
                racc[r] = fmaf(wv.w, xv.w, racc[r]);
            }
        }
        #pragma unroll
        for (int r = 0; r < 4; r++) {
            racc[r] += __shfl_xor(racc[r], 1, 64);
            racc[r] += __shfl_xor(racc[r], 2, 64);
            racc[r] += __shfl_xor(racc[r], 4, 64);
            racc[r] += __shfl_xor(racc[r], 8, 64);
        }
        if (kl == 0) {
            float bb = beff[o];
            #pragma unroll
            for (int r = 0; r < 4; r++)
                c2t[(size_t)(row0 + r) * 512 + o] = f2bf_u(racc[r] + bb);
        }
    }
}

// B2 phase: blocks 0..127, 4 rows each.
__device__ void b2_phase(float* __restrict__ sm,
                         const u16* __restrict__ c2t, const float* __restrict__ h2,
                         const float* __restrict__ Wc22, const float* __restrict__ bc22,
                         const float* __restrict__ lg2, const float* __restrict__ lb2,
                         const float* __restrict__ Wnn1, const float* __restrict__ bnn1,
                         const float* __restrict__ g3, const float* __restrict__ b3v,
                         const float* __restrict__ Wnn2, const float* __restrict__ bnn2,
                         float* __restrict__ outt) {
    float* x_s = sm;             // 4*1024
    float* y_s = sm + 4 * 1024;  // 4*512
    const int tid = threadIdx.x;
    const int row0 = blockIdx.x * 4;
    for (int i = tid; i < 4 * 512; i += 256) {
        int r = i >> 9, k = i & 511;
        x_s[r * 1024 + k] = bfu(c2t[(size_t)(row0 + r) * 512 + k]);
        x_s[r * 1024 + 512 + k] = h2[(size_t)(row0 + r) * 512 + k];
    }
    __syncthreads();
    const int w = tid >> 6, lane = tid & 63;
    const int cg_ = lane >> 4, kl = lane & 15;
    for (int i = 0; i < 32; i++) {
        int o = i * 16 + w * 4 + cg_;
        const float* wrow = Wc22 + (size_t)o * 1024;
        float racc[4] = {0.f, 0.f, 0.f, 0.f};
        #pragma unroll
        for (int g = 0; g < 16; g++) {
            int k = g * 64 + kl * 4;
            float4 wv = *(const float4*)(wrow + k);
            #pragma unroll
            for (int r = 0; r < 4; r++) {
                float4 xv = *(const float4*)(x_s + r * 1024 + k);
                racc[r] = fmaf(wv.x, xv.x, racc[r]);
                racc[r] = fmaf(wv.y, xv.y, racc[r]);
                racc[r] = fmaf(wv.z, xv.z, racc[r]);
                racc[r] = fmaf(wv.w, xv.w, racc[r]);
            }
        }
        #pragma unroll
        for (int r = 0; r < 4; r++) {
            racc[r] += __shfl_xor(racc[r], 1, 64);
            racc[r] += __shfl_xor(racc[r], 2, 64);
            racc[r] += __shfl_xor(racc[r], 4, 64);
            racc[r] += __shfl_xor(racc[r], 8, 64);
        }
        if (kl == 0) {
            float bb = bc22[o];
            #pragma unroll
            for (int r = 0; r < 4; r++) y_s[r * 512 + o] = racc[r] + bb;
        }
    }
    __syncthreads();
    {
        float v[8], sum = 0.f, ssq = 0.f;
        #pragma unroll
        for (int j = 0; j < 8; j++) {
            v[j] = y_s[w * 512 + lane * 8 + j];
            sum += v[j]; ssq += v[j] * v[j];
        }
        #pragma unroll
        for (int m = 1; m < 64; m <<= 1) {
            sum += __shfl_xor(sum, m, 64);
            ssq += __shfl_xor(ssq, m, 64);
        }
        float mu = sum * (1.f / 512.f);
        float rstd = rsqrtf(ssq * (1.f / 512.f) - mu * mu + 1e-5f);
        #pragma unroll
        for (int j = 0; j < 8; j++) {
            int o = lane * 8 + j;
            y_s[w * 512 + o] = (v[j] - mu) * rstd * lg2[o] + lb2[o];
        }
    }
    __syncthreads();
    {
        float p[8];
        const float* yp = y_s + w * 512 + lane * 8;
        #pragma unroll
        for (int o8 = 0; o8 < 8; o8++) {
            const float* wp = Wnn1 + o8 * 512 + lane * 8;
            float s = 0.f;
            #pragma unroll
            for (int j = 0; j < 8; j++) s = fmaf(yp[j], wp[j], s);
            p[o8] = s;
        }
        #pragma unroll
        for (int m = 1; m < 64; m <<= 1) {
            #pragma unroll
            for (int o8 = 0; o8 < 8; o8++) p[o8] += __shfl_xor(p[o8], m, 64);
        }
        if (lane == 0) {
            float tv[8], m8 = 0.f;
            #pragma unroll
            for (int o8 = 0; o8 < 8; o8++) {
                tv[o8] = fmaxf(p[o8] + bnn1[o8], 0.f);
                m8 += tv[o8];
            }
            m8 *= 0.125f;
            float var = 0.f;
            #pragma unroll
            for (int o8 = 0; o8 < 8; o8++) { float d = tv[o8] - m8; var += d * d; }
            var *= 0.125f;
            const float rstd8 = rsqrtf(var + 1e-5f);
            float o0v = bnn2[0], o1v = bnn2[1];
            #pragma unroll
            for (int o8 = 0; o8 < 8; o8++) {
                float v = (tv[o8] - m8) * rstd8 * g3[o8] + b3v[o8];
                o0v += v * Wnn2[o8];
                o1v += v * Wnn2[8 + o8];
            }
            outt[(row0 + w) * 2 + 0] = o0v;
            outt[(row0 + w) * 2 + 1] = o1v;
        }
    }
}

// ---- cooperative persistent scan: 4 grid.syncs/step ----
__global__ __launch_bounds__(256, 2)
void k_scan(const u16* __restrict__ comb1, const float* __restrict__ mask,
            const float* __restrict__ Wih1, const float* __restrict__ Whh1,
            const float* __restrict__ bih1, const float* __restrict__ bhh1,
            const float* __restrict__ Wc21, const float* __restrict__ bc21,
            const float* __restrict__ lg1, const float* __restrict__ lb1,
            const float* __restrict__ Wcomb2, const float* __restrict__ beff,
            const float* __restrict__ Wih2, const float* __restrict__ Whh2,
            const float* __restrict__ bih2, const float* __restrict__ bhh2,
            const float* __restrict__ Wc22, const float* __restrict__ bc22,
            const float* __restrict__ lg2, const float* __restrict__ lb2,
            const float* __restrict__ Wnn1, const float* __restrict__ bnn1,
            const float* __restrict__ g3, const float* __restrict__ b3v,
            const float* __restrict__ Wnn2, const float* __restrict__ bnn2,
            float* __restrict__ h1a, float* __restrict__ h1b,
            float* __restrict__ h2a, float* __restrict__ h2b,
            u16* __restrict__ c2t, float* __restrict__ out) {
    cg::grid_group grid = cg::this_grid();
    __shared__ float sm[SM_FLOATS];

    for (int t = 0; t < S_; t++) {
        const float* h1c = (t & 1) ? h1b : h1a;
        float*       h1n = (t & 1) ? h1a : h1b;
        const float* h2c = (t & 1) ? h2b : h2a;
        float*       h2n = (t & 1) ? h2a : h2b;
        const float* maskRow = mask + (size_t)t * B_;

        gru_phase<64>(sm, comb1 + (size_t)t * B_ * 64, Wih1, Whh1, bih1, bhh1,
                      maskRow, h1c, h1n);
        __threadfence();
        grid.sync();

        if (blockIdx.x < 128)
            b1_phase(sm, comb1 + (size_t)t * B_ * 64, h1n, Wc21, bc21, lg1, lb1,
                     Wcomb2, beff, c2t);
        __threadfence();
        grid.sync();

        gru_phase<512>(sm, c2t, Wih2, Whh2, bih2, bhh2, maskRow, h2c, h2n);
        __threadfence();
        grid.sync();

        if (blockIdx.x < 128)
            b2_phase(sm, c2t, h2n, Wc22, bc22, lg2, lb2, Wnn1, bnn1, g3, b3v,
                     Wnn2, bnn2, out + (size_t)t * B_ * 2);
        __threadfence();
        grid.sync();
    }
}

// ---- fallback per-step wrappers (round-4 proven path) ----
template<int D>
__global__ __launch_bounds__(256, 2)
void k_gru_fb(const u16* __restrict__ comb_t, const float* __restrict__ Wih,
              const float* __restrict__ Whh, const float* __restrict__ bih,
              const float* __restrict__ bhh, const float* __restrict__ maskRow,
              const float* __restrict__ hcur, float* __restrict__ hnxt) {
    __shared__ float sm[SM_FLOATS];
    gru_phase<D>(sm, comb_t, Wih, Whh, bih, bhh, maskRow, hcur, hnxt);
}

__global__ __launch_bounds__(256, 2)
void k_b1_fb(const u16* __restrict__ c1t, const float* __restrict__ h1,
             const float* __restrict__ Wc21, const float* __restrict__ bc21,
             const float* __restrict__ lg1, const float* __restrict__ lb1,
             const float* __restrict__ Wcomb2, const float* __restrict__ beff,
             u16* __restrict__ c2t) {
    __shared__ float sm[SM_FLOATS];
    b1_phase(sm, c1t, h1, Wc21, bc21, lg1, lb1, Wcomb2, beff, c2t);
}

__global__ __launch_bounds__(256, 2)
void k_b2_fb(const u16* __restrict__ c2t, const float* __restrict__ h2,
             const float* __restrict__ Wc22, const float* __restrict__ bc22,
             const float* __restrict__ lg2, const float* __restrict__ lb2,
             const float* __restrict__ Wnn1, const float* __restrict__ bnn1,
             const float* __restrict__ g3, const float* __restrict__ b3v,
             const float* __restrict__ Wnn2, const float* __restrict__ bnn2,
             float* __restrict__ outt) {
    __shared__ float sm[SM_FLOATS];
    b2_phase(sm, c2t, h2, Wc22, bc22, lg2, lb2, Wnn1, bnn1, g3, b3v, Wnn2, bnn2, outt);
}

extern "C" void kernel_launch(void* const* d_in, const int* in_sizes, int n_in,
                              void* d_out, int out_size, void* d_ws, size_t ws_size,
                              hipStream_t stream) {
    const float* X      = (const float*)d_in[0];
    const float* M      = (const float*)d_in[1];
    const float* mask   = (const float*)d_in[2];
    const float* Wi2h   = (const float*)d_in[3];
    const float* bi2h   = (const float*)d_in[4];
    const float* Wcomb1 = (const float*)d_in[5];
    const float* bcomb1 = (const float*)d_in[6];
    const float* Wih1   = (const float*)d_in[7];
    const float* Whh1   = (const float*)d_in[8];
    const float* bih1   = (const float*)d_in[9];
    const float* bhh1   = (const float*)d_in[10];
    const float* Wc21   = (const float*)d_in[11];
    const float* bc21   = (const float*)d_in[12];
    const float* Wcomb2 = (const float*)d_in[13];
    const float* bcomb2 = (const float*)d_in[14];
    const float* Wih2   = (const float*)d_in[15];
    const float* Whh2   = (const float*)d_in[16];
    const float* bih2   = (const float*)d_in[17];
    const float* bhh2   = (const float*)d_in[18];
    const float* Wc22   = (const float*)d_in[19];
    const float* bc22   = (const float*)d_in[20];
    const float* g1     = (const float*)d_in[21];
    const float* b1     = (const float*)d_in[22];
    const float* g2     = (const float*)d_in[23];
    const float* b2     = (const float*)d_in[24];
    const float* g3     = (const float*)d_in[25];
    const float* b3     = (const float*)d_in[26];
    const float* Wnn1   = (const float*)d_in[27];
    const float* bnn1   = (const float*)d_in[28];
    const float* Wnn2   = (const float*)d_in[29];
    const float* bnn2   = (const float*)d_in[30];
    float* out = (float*)d_out;

    const size_t SZ_COMB1 = (size_t)S_ * B_ * 64 * 2;
    const size_t SZ_HX    = (size_t)B_ * H_ * 4;
    const size_t SZ_C2T   = (size_t)B_ * 512 * 2;
    const size_t NEED = SZ_COMB1 + 4 * SZ_HX + SZ_C2T + 8192;
    if (ws_size < NEED) {
        float v = 1.0e4f + (float)(ws_size >> 20);
        k_sentinel<<<(out_size + 255) / 256, 256, 0, stream>>>(out, out_size, v);
        return;
    }
    char* ws = (char*)d_ws;
    u16* comb1 = (u16*)ws;   ws += SZ_COMB1;
    float* h1a = (float*)ws; ws += SZ_HX;
    float* h1b = (float*)ws; ws += SZ_HX;
    float* h2a = (float*)ws; ws += SZ_HX;
    float* h2b = (float*)ws; ws += SZ_HX;
    u16* c2t   = (u16*)ws;   ws += SZ_C2T;
    float* beff = (float*)ws; ws += 512 * 4;

    k_h0<<<1024, 256, 0, stream>>>(X, Wi2h, bi2h, h1a, h2a);
    k_beff<<<2, 256, 0, stream>>>(Wcomb2, bcomb2, beff);
    k_comb1<<<8192, 256, 0, stream>>>(X, M, Wcomb1, bcomb1, comb1);

    // ---- try cooperative persistent scan; fall back on error ----
    const u16* a_comb1 = comb1; const float* a_mask = mask;
    const float* a_Wih1 = Wih1; const float* a_Whh1 = Whh1;
    const float* a_bih1 = bih1; const float* a_bhh1 = bhh1;
    const float* a_Wc21 = Wc21; const float* a_bc21 = bc21;
    const float* a_g1 = g1; const float* a_b1 = b1;
    const float* a_Wcomb2 = Wcomb2; const float* a_beff = beff;
    const float* a_Wih2 = Wih2; const float* a_Whh2 = Whh2;
    const float* a_bih2 = bih2; const float* a_bhh2 = bhh2;
    const float* a_Wc22 = Wc22; const float* a_bc22 = bc22;
    const float* a_g2 = g2; const float* a_b2 = b2;
    const float* a_Wnn1 = Wnn1; const float* a_bnn1 = bnn1;
    const float* a_g3 = g3; const float* a_b3 = b3;
    const float* a_Wnn2 = Wnn2; const float* a_bnn2 = bnn2;
    float* a_h1a = h1a; float* a_h1b = h1b;
    float* a_h2a = h2a; float* a_h2b = h2b;
    u16* a_c2t = c2t; float* a_out = out;
    void* args[] = {
        &a_comb1, &a_mask,
        &a_Wih1, &a_Whh1, &a_bih1, &a_bhh1,
        &a_Wc21, &a_bc21, &a_g1, &a_b1,
        &a_Wcomb2, &a_beff,
        &a_Wih2, &a_Whh2, &a_bih2, &a_bhh2,
        &a_Wc22, &a_bc22, &a_g2, &a_b2,
        &a_Wnn1, &a_bnn1, &a_g3, &a_b3, &a_Wnn2, &a_bnn2,
        &a_h1a, &a_h1b, &a_h2a, &a_h2b, &a_c2t, &a_out
    };
    hipError_t cerr = hipLaunchCooperativeKernel((const void*)k_scan, dim3(512),
                                                 dim3(256), args, 0, stream);
    if (cerr != hipSuccess) {
        // fallback: per-step multi-launch (proven in round 4)
        for (int t = 0; t < S_; t++) {
            const float* h1c = (t & 1) ? h1b : h1a;
            float*       h1n = (t & 1) ? h1a : h1b;
            const float* h2c = (t & 1) ? h2b : h2a;
            float*       h2n = (t & 1) ? h2a : h2b;
            const float* maskRow = mask + (size_t)t * B_;
            k_gru_fb<64><<<512, 256, 0, stream>>>(
                comb1 + (size_t)t * B_ * 64, Wih1, Whh1, bih1, bhh1,
                maskRow, h1c, h1n);
            k_b1_fb<<<128, 256, 0, stream>>>(
                comb1 + (size_t)t * B_ * 64, h1n, Wc21, bc21, g1, b1,
                Wcomb2, beff, c2t);
            k_gru_fb<512><<<512, 256, 0, stream>>>(
                c2t, Wih2, Whh2, bih2, bhh2, maskRow, h2c, h2n);
            k_b2_fb<<<128, 256, 0, stream>>>(
                c2t, h2n, Wc22, bc22, g2, b2, Wnn1, bnn1, g3, b3,
                Wnn2, bnn2, out + (size_t)t * B_ * 2);
        }
    }
}